// Round 3
// baseline (366.865 us; speedup 1.0000x reference)
//
#include <hip/hip_runtime.h>
#include <stdint.h>

// CausalConv1d: B=4, L=4096, D=2048, K=4, G=8
//   out[b,l,o] = sum_{k,i} x[b, l+k-3, g*256+i] * w[k,i,o],  g = o>>8
// R3: bf16 MFMA 16x16x32, implicit im2col.
//   - B (weights) loaded global->registers per k-step (no LDS, no barrier coupling);
//     XCD swizzle keeps each XCD's 512 KB wt slice L2-resident.
//   - A double-buffered in LDS (As[2][131][72]), staged via reg prefetch; 4 barriers total.

#define CC_L 4096
#define CC_D 2048

typedef float f32x4 __attribute__((ext_vector_type(4)));
typedef __bf16 bf16x8 __attribute__((ext_vector_type(8)));

static __device__ __forceinline__ unsigned short f2bf(float f) {
    union { float f; uint32_t u; } v; v.f = f;
    uint32_t u = v.u;
    u += 0x7fffu + ((u >> 16) & 1u);   // round-to-nearest-even
    return (unsigned short)(u >> 16);
}

// ---------------------------------------------------------------------------
// prep: wt[o][k*256+i] = bf16(w[k][i][o]).  fp32 LDS transpose (+1 pad: 2-way
// write / 4-way read banks, vs R2's 2-bank ushort pathology).
// grid = 4k * 32 o-tiles * 2 i-halves = 256 blocks, 256 threads.
__global__ __launch_bounds__(256) void cc_prep_w(const float* __restrict__ w,
                                                 unsigned short* __restrict__ wt) {
    __shared__ float T[64][129];
    const int tid = threadIdx.x;
    const int k  = blockIdx.x >> 6;
    const int ot = (blockIdx.x >> 1) & 31;
    const int ih = blockIdx.x & 1;
    const int o0 = ot << 6;
    const int i0 = ih << 7;

#pragma unroll
    for (int it = 0; it < 8; ++it) {
        int i  = it * 16 + (tid >> 4);          // 0..127
        int oc = (tid & 15) << 2;               // 0..60
        const float4 v = *(const float4*)(w + ((size_t)(k * 256 + i0 + i)) * CC_D + o0 + oc);
        T[oc + 0][i] = v.x;
        T[oc + 1][i] = v.y;
        T[oc + 2][i] = v.z;
        T[oc + 3][i] = v.w;
    }
    __syncthreads();
#pragma unroll
    for (int it = 0; it < 4; ++it) {
        int o  = it * 16 + (tid >> 4);          // 0..63
        int ic = (tid & 15) << 3;               // 0..120
        ushort4 h0, h1;
        h0.x = f2bf(T[o][ic + 0]); h0.y = f2bf(T[o][ic + 1]);
        h0.z = f2bf(T[o][ic + 2]); h0.w = f2bf(T[o][ic + 3]);
        h1.x = f2bf(T[o][ic + 4]); h1.y = f2bf(T[o][ic + 5]);
        h1.z = f2bf(T[o][ic + 6]); h1.w = f2bf(T[o][ic + 7]);
        unsigned short* dst = wt + (size_t)(o0 + o) * 1024 + k * 256 + i0 + ic;
        *(ushort4*)(dst + 0) = h0;
        *(ushort4*)(dst + 4) = h1;
    }
}

// ---------------------------------------------------------------------------
// conv: grid 2048 blocks, 256 threads (4 waves 2x2), 128x128 tile.
// XCD swizzle: xcd = bid&7 owns group xcd (tileN in {2*xcd, 2*xcd+1}).
__global__ __launch_bounds__(256, 3) void cc_conv(const float* __restrict__ x,
                                                  const unsigned short* __restrict__ wt,
                                                  float* __restrict__ out) {
    __shared__ unsigned short As[2][131][72];   // padded; 37.7 KB total

    const int tid   = threadIdx.x;
    const int bid   = blockIdx.x;
    const int xcd   = bid & 7;
    const int jj    = bid >> 3;                 // 0..255
    const int tileN = (xcd << 1) | (jj >> 7);
    const int tileM = jj & 127;
    const int n0    = tileN << 7;
    const int g     = tileN >> 1;
    const int cin   = g << 8;
    const int m0    = tileM << 7;
    const int b     = m0 >> 12;                 // tiles never span batches
    const int l0    = m0 & (CC_L - 1);

    const int lane = tid & 63;
    const int wv   = tid >> 6;
    const int wm   = (wv & 1) << 6;
    const int wn   = (wv >> 1) << 6;
    const int lr   = lane & 15;
    const int quad = lane >> 4;

    const float* xg = x + (size_t)b * CC_L * CC_D + cin;
    // B fragment base pointers: lane-fixed row (n0+wn+f*16+lr), chunk quad*8.
    // Per-(cc,kf,ks) offsets are <=1984 B immediates.
    const unsigned short* wp = wt + (size_t)(n0 + wn + lr) * 1024 + (quad << 3);

    f32x4 acc[4][4];
#pragma unroll
    for (int i = 0; i < 4; ++i)
#pragma unroll
        for (int j = 0; j < 4; ++j) acc[i][j] = (f32x4){0.f, 0.f, 0.f, 0.f};

    // ---- A staging: 128 main rows (8 f4/thread) + 3 halo rows ----
    const int f4 = tid & 15;
    const int rb = tid >> 4;
    float4 avm[8];
    float4 avh;

#define LOAD_A(cc)                                                                  \
    {                                                                               \
        _Pragma("unroll")                                                           \
        for (int j = 0; j < 8; ++j) {                                               \
            int l = l0 + rb + j * 16;                                               \
            avm[j] = *(const float4*)(xg + (size_t)l * CC_D + ((cc) << 6) + (f4 << 2)); \
        }                                                                           \
        if (tid < 48) {                                                             \
            int l = l0 - 3 + (tid >> 4);                                            \
            avh = *(const float4*)(xg + (size_t)(l < 0 ? 0 : l) * CC_D + ((cc) << 6) + (f4 << 2)); \
        }                                                                           \
    }

#define WRITE_A(dbuf)                                                               \
    {                                                                               \
        _Pragma("unroll")                                                           \
        for (int j = 0; j < 8; ++j) {                                               \
            ushort4 h;                                                              \
            h.x = f2bf(avm[j].x); h.y = f2bf(avm[j].y);                             \
            h.z = f2bf(avm[j].z); h.w = f2bf(avm[j].w);                             \
            *(ushort4*)&As[dbuf][rb + j * 16 + 3][f4 << 2] = h;                     \
        }                                                                           \
        if (tid < 48) {                                                             \
            ushort4 h = {0, 0, 0, 0};                                               \
            if (l0 > 0) {                                                           \
                h.x = f2bf(avh.x); h.y = f2bf(avh.y);                               \
                h.z = f2bf(avh.z); h.w = f2bf(avh.w);                               \
            }                                                                       \
            *(ushort4*)&As[dbuf][tid >> 4][f4 << 2] = h;                            \
        }                                                                           \
    }

    // ---- prologue: stage A(0) into buf 0 ----
    LOAD_A(0);
    WRITE_A(0);
    __syncthreads();

    // ---- main loop: K = 4 cc-chunks x 4 kf x 2 ks; 1 barrier per cc ----
#pragma unroll
    for (int cc = 0; cc < 4; ++cc) {
        const int buf = cc & 1;
        if (cc < 3) LOAD_A(cc + 1);             // issue early; lands before WRITE_A
#pragma unroll
        for (int kf = 0; kf < 4; ++kf) {
            bf16x8 a[2][4], bb[2][4];
#pragma unroll
            for (int ks = 0; ks < 2; ++ks)
#pragma unroll
                for (int f = 0; f < 4; ++f)
                    bb[ks][f] = *(const bf16x8*)(wp + (size_t)f * 16384
                                                 + kf * 256 + cc * 64 + ks * 32);
#pragma unroll
            for (int ks = 0; ks < 2; ++ks)
#pragma unroll
                for (int f = 0; f < 4; ++f)
                    a[ks][f] = *(const bf16x8*)&As[buf][wm + f * 16 + lr + kf]
                                                  [(ks << 5) + (quad << 3)];
#pragma unroll
            for (int ks = 0; ks < 2; ++ks)
#pragma unroll
                for (int fm = 0; fm < 4; ++fm)
#pragma unroll
                    for (int fn = 0; fn < 4; ++fn)
                        acc[fm][fn] = __builtin_amdgcn_mfma_f32_16x16x32_bf16(
                            a[ks][fm], bb[ks][fn], acc[fm][fn], 0, 0, 0);
        }
        if (cc < 3) {
            WRITE_A(buf ^ 1);   // safe: buf^1 last read in cc-1, barrier passed
            __syncthreads();
        }
    }

    // ---- epilogue: C/D layout col = lane&15, row = quad*4 + reg ----
    const size_t obase = (size_t)m0 * CC_D + n0;
#pragma unroll
    for (int fm = 0; fm < 4; ++fm)
#pragma unroll
        for (int fn = 0; fn < 4; ++fn) {
            int ml = wm + fm * 16 + quad * 4;
            int nl = wn + fn * 16 + lr;
#pragma unroll
            for (int r = 0; r < 4; ++r)
                out[obase + (size_t)(ml + r) * CC_D + nl] = acc[fm][fn][r];
        }
}

extern "C" void kernel_launch(void* const* d_in, const int* in_sizes, int n_in,
                              void* d_out, int out_size, void* d_ws, size_t ws_size,
                              hipStream_t stream) {
    const float* x = (const float*)d_in[0];
    const float* w = (const float*)d_in[1];
    float* out = (float*)d_out;
    unsigned short* wt = (unsigned short*)d_ws;   // 2048*1024 bf16 = 4 MB

    cc_prep_w<<<256, 256, 0, stream>>>(w, wt);
    cc_conv<<<2048, 256, 0, stream>>>(x, wt, out);
}